// Round 3
// baseline (291.811 us; speedup 1.0000x reference)
//
#include <hip/hip_runtime.h>
#include <math.h>

#define BB   32
#define CC   512
#define HWW  1024
#define OUTC 256
#define EPSV 1e-5f

typedef __attribute__((ext_vector_type(8))) short bfrag;
typedef __attribute__((ext_vector_type(4))) float f32x4;

__device__ inline unsigned short f2bf(float x){
  unsigned int uu = __float_as_uint(x);
  uu += 0x7fff + ((uu >> 16) & 1);      // round-to-nearest-even
  return (unsigned short)(uu >> 16);
}
__device__ inline float bf2f(unsigned short h){
  return __uint_as_float(((unsigned int)h) << 16);
}

#define ASYNC16(g, l) \
  __builtin_amdgcn_global_load_lds((const __attribute__((address_space(1))) unsigned int*)(g), \
                                   (__attribute__((address_space(3))) unsigned int*)(l), 16, 0, 0)

// ===========================================================================
// NEW PATH (split-bf16 MFMA)
// ===========================================================================

// --- prep: merged weight-convert (z==32) + x hi/lo + transpose (z<32) -------
__global__ __launch_bounds__(256) void prep(
    const float* __restrict__ x,
    const float* __restrict__ w1, const float* __restrict__ w2,
    const float* __restrict__ w3,
    unsigned short* __restrict__ Xhi, unsigned short* __restrict__ Xlo,
    unsigned short* __restrict__ XThi,
    unsigned short* __restrict__ Whi, unsigned short* __restrict__ Wlo,
    unsigned short* __restrict__ W3hi)
{
  if (blockIdx.z == 32) {
    // weight conversion: 512*1024 (w1|w2 split) + 512*512 (w3 bf16)
    int worker = (blockIdx.y * 16 + blockIdx.x) * 256 + threadIdx.x;  // < 32768
    for (int i = worker; i < 786432; i += 32768) {
      if (i < 524288) {
        float v = (i < 262144) ? w1[i] : w2[i - 262144];
        unsigned short h = f2bf(v);
        Whi[i] = h;
        Wlo[i] = f2bf(v - bf2f(h));
      } else {
        int j = i - 524288;
        W3hi[j] = f2bf(w3[j]);
      }
    }
    return;
  }
  __shared__ float T[64][65];
  const int b = blockIdx.z, c0 = blockIdx.y * 64, p0 = blockIdx.x * 64;
  const int tid = threadIdx.x, tr = tid >> 4, tc4 = (tid & 15) * 4;
  const float* xb = x + (size_t)b * 512 * 1024;
#pragma unroll
  for (int r = 0; r < 4; ++r) {
    int c = c0 + tr + r * 16;
    float4 v = *(const float4*)(xb + (size_t)c * 1024 + p0 + tc4);
    T[tr + r * 16][tc4 + 0] = v.x; T[tr + r * 16][tc4 + 1] = v.y;
    T[tr + r * 16][tc4 + 2] = v.z; T[tr + r * 16][tc4 + 3] = v.w;
    ushort4 h, l;
    h.x = f2bf(v.x); l.x = f2bf(v.x - bf2f(h.x));
    h.y = f2bf(v.y); l.y = f2bf(v.y - bf2f(h.y));
    h.z = f2bf(v.z); l.z = f2bf(v.z - bf2f(h.z));
    h.w = f2bf(v.w); l.w = f2bf(v.w - bf2f(h.w));
    size_t idx = (size_t)b * 524288 + (size_t)c * 1024 + p0 + tc4;
    *(ushort4*)(Xhi + idx) = h;
    *(ushort4*)(Xlo + idx) = l;
  }
  __syncthreads();
#pragma unroll
  for (int r = 0; r < 4; ++r) {
    int pl = tr + r * 16;
    ushort4 h;
    h.x = f2bf(T[tc4 + 0][pl]); h.y = f2bf(T[tc4 + 1][pl]);
    h.z = f2bf(T[tc4 + 2][pl]); h.w = f2bf(T[tc4 + 3][pl]);
    *(ushort4*)(XThi + (size_t)b * 524288 + (size_t)(p0 + pl) * 512 + c0 + tc4) = h;
  }
}

// --- g1: P2[b][c][oo] = relu(bn(sum_q x[b][c][q]*W[oo][q] + bias)) ----------
// split-bf16 (3 MFMAs); 128x128 tile; global_load_lds w=16.
// XCD swizzle: blocks sharing an X-tile (same b,c, 4 n-values) land on the
// same XCD (linear-id mod 8). XOR swizzle on staging k-chunk kills the 4-way
// LDS bank conflict on fragment ds_read_b128.
// Epilogue also accumulates u/t partials (was k3): per-block sum over the
// 128 c-rows of w4a/w4b * relu'd value, atomicAdd into u/t.
__global__ __launch_bounds__(256) void g1_mfma(
    const unsigned short* __restrict__ Xhi, const unsigned short* __restrict__ Xlo,
    const unsigned short* __restrict__ Whi, const unsigned short* __restrict__ Wlo,
    const float* __restrict__ b1p, const float* __restrict__ g1p,
    const float* __restrict__ be1p, const float* __restrict__ m1p, const float* __restrict__ v1p,
    const float* __restrict__ b2p, const float* __restrict__ g2p,
    const float* __restrict__ be2p, const float* __restrict__ m2p, const float* __restrict__ v2p,
    const float* __restrict__ w4,
    float* __restrict__ P2, float* __restrict__ u, float* __restrict__ t)
{
  __shared__ unsigned short sAh[4096], sAl[4096], sBh[4096], sBl[4096];
  // ---- XCD-aware block decode: f = xcd + 8*n + 32*group_hi ----
  const int f    = blockIdx.x;
  const int xcd  = f & 7;
  const int n0   = ((f >> 3) & 3) * 128;            // oo tile
  const int g    = ((f >> 5) << 3) | xcd;           // 0..127
  const int b    = g >> 2;
  const int c0   = (g & 3) * 128;                   // c tile
  const int tid  = threadIdx.x;
  const int wave = tid >> 6, lane = tid & 63;
  const int lr = lane >> 2;
  const int lcs = ((lane & 3) ^ (lr & 3)) * 8;      // swizzled 16B chunk (shorts)
  const int wm = wave & 1, wn = wave >> 1;
  const int fr = lane & 15, fq = lane >> 4;
  const int fsw = (fq ^ (fr & 3)) * 8;              // fragment chunk offset (shorts)

  const unsigned short* gb; unsigned short* lb;
  if (wave == 0)      { gb = Xhi + (size_t)b * 524288 + (size_t)c0 * 1024; lb = sAh; }
  else if (wave == 1) { gb = Xlo + (size_t)b * 524288 + (size_t)c0 * 1024; lb = sAl; }
  else if (wave == 2) { gb = Whi + (size_t)n0 * 1024; lb = sBh; }
  else                { gb = Wlo + (size_t)n0 * 1024; lb = sBl; }
  gb += (size_t)lr * 1024 + lcs;

  f32x4 acc[4][4];
  const f32x4 zz = {0.f, 0.f, 0.f, 0.f};
#pragma unroll
  for (int i = 0; i < 4; ++i)
#pragma unroll
    for (int j = 0; j < 4; ++j) acc[i][j] = zz;

  for (int kq = 0; kq < 1024; kq += 32) {
#pragma unroll
    for (int inst = 0; inst < 8; ++inst)
      ASYNC16(gb + (size_t)inst * 16 * 1024 + kq, lb + inst * 512);
    __syncthreads();
    bfrag ah[4], al[4], bh[4], bl[4];
#pragma unroll
    for (int i = 0; i < 4; ++i) {
      int off = (wm * 64 + i * 16 + fr) * 32 + fsw;
      ah[i] = *(const bfrag*)&sAh[off];
      al[i] = *(const bfrag*)&sAl[off];
    }
#pragma unroll
    for (int j = 0; j < 4; ++j) {
      int off = (wn * 64 + j * 16 + fr) * 32 + fsw;
      bh[j] = *(const bfrag*)&sBh[off];
      bl[j] = *(const bfrag*)&sBl[off];
    }
#pragma unroll
    for (int i = 0; i < 4; ++i)
#pragma unroll
      for (int j = 0; j < 4; ++j) {
        acc[i][j] = __builtin_amdgcn_mfma_f32_16x16x32_bf16(ah[i], bh[j], acc[i][j], 0, 0, 0);
        acc[i][j] = __builtin_amdgcn_mfma_f32_16x16x32_bf16(ah[i], bl[j], acc[i][j], 0, 0, 0);
        acc[i][j] = __builtin_amdgcn_mfma_f32_16x16x32_bf16(al[i], bh[j], acc[i][j], 0, 0, 0);
      }
    __syncthreads();
  }

  // ---- epilogue: bn params are block-uniform in the theta/phi sense ----
  const float *bias, *gg, *bes, *mm, *vv_; int cof;
  if (n0 < 256) { bias = b1p; gg = g1p; bes = be1p; mm = m1p; vv_ = v1p; cof = 0; }
  else          { bias = b2p; gg = g2p; bes = be2p; mm = m2p; vv_ = v2p; cof = 256; }
  // hoisted w4 weights for u/t partials (same for all j):
  // n0<256 -> theta columns -> t with w4[513+crow]; else phi -> u with w4[1+crow]
  const float* wsel = (n0 < 256) ? (w4 + 513) : (w4 + 1);
  float* dsel = (n0 < 256) ? (t + b * 256) : (u + b * 256);
  const int cobase = ((n0 < 256) ? n0 : n0 - 256) + wn * 64;
  float wt[4][4];
#pragma unroll
  for (int i = 0; i < 4; ++i)
#pragma unroll
    for (int r = 0; r < 4; ++r)
      wt[i][r] = wsel[c0 + wm * 64 + i * 16 + fq * 4 + r];

#pragma unroll
  for (int j = 0; j < 4; ++j) {
    int co = n0 + wn * 64 + j * 16 + fr;
    int q = co - cof;
    float s  = gg[q] * rsqrtf(vv_[q] + EPSV);
    float sh = (bias[q] - mm[q]) * s + bes[q];
    float psum = 0.f;
#pragma unroll
    for (int i = 0; i < 4; ++i) {
      int crow = c0 + wm * 64 + i * 16 + fq * 4;
      float* dst = P2 + ((size_t)b * 512 + crow) * 512 + co;
#pragma unroll
      for (int r = 0; r < 4; ++r) {
        float val = fmaxf(acc[i][j][r] * s + sh, 0.f);
        dst[(size_t)r * 512] = val;
        psum += wt[i][r] * val;
      }
    }
    psum += __shfl_xor(psum, 16);
    psum += __shfl_xor(psum, 32);
    if (fq == 0) atomicAdd(&dsel[cobase + j * 16 + fr], psum);
  }
}

// --- g2: xe_acc[b][o] += sum_p relu(bn(sum_c w3[o][c]*x[b][c][p])) ----------
// pure bf16 (error budget fine); same XOR-swizzle as g1. Grid layout already
// XCD-friendly (o-blocks sharing an XThi tile differ by 8 in linear id).
__global__ __launch_bounds__(256) void g2_mfma(
    const unsigned short* __restrict__ W3hi, const unsigned short* __restrict__ XThi,
    const float* __restrict__ b3p, const float* __restrict__ g3p,
    const float* __restrict__ be3p, const float* __restrict__ m3p, const float* __restrict__ v3p,
    float* __restrict__ xe_acc)
{
  __shared__ unsigned short sA[4096], sB[4096];
  const int b  = blockIdx.z;
  const int n0 = blockIdx.x * 128;   // p
  const int m0 = blockIdx.y * 128;   // o
  const int tid = threadIdx.x;
  const int wave = tid >> 6, lane = tid & 63;
  const int lr = lane >> 2;
  const int lcs = ((lane & 3) ^ (lr & 3)) * 8;
  const int wm = wave & 1, wn = wave >> 1;
  const int fr = lane & 15, fq = lane >> 4;
  const int fsw = (fq ^ (fr & 3)) * 8;

  const unsigned short* gb; unsigned short* lb;
  if (wave < 2) { gb = W3hi + (size_t)(m0 + wave * 64) * 512; lb = sA + wave * 2048; }
  else { gb = XThi + (size_t)b * 524288 + (size_t)(n0 + (wave - 2) * 64) * 512; lb = sB + (wave - 2) * 2048; }
  gb += (size_t)lr * 512 + lcs;

  f32x4 acc[4][4];
  const f32x4 zz = {0.f, 0.f, 0.f, 0.f};
#pragma unroll
  for (int i = 0; i < 4; ++i)
#pragma unroll
    for (int j = 0; j < 4; ++j) acc[i][j] = zz;

  for (int kq = 0; kq < 512; kq += 32) {
#pragma unroll
    for (int inst = 0; inst < 4; ++inst)
      ASYNC16(gb + (size_t)inst * 16 * 512 + kq, lb + inst * 512);
    __syncthreads();
    bfrag af[4], bf[4];
#pragma unroll
    for (int i = 0; i < 4; ++i)
      af[i] = *(const bfrag*)&sA[(wm * 64 + i * 16 + fr) * 32 + fsw];
#pragma unroll
    for (int j = 0; j < 4; ++j)
      bf[j] = *(const bfrag*)&sB[(wn * 64 + j * 16 + fr) * 32 + fsw];
#pragma unroll
    for (int i = 0; i < 4; ++i)
#pragma unroll
      for (int j = 0; j < 4; ++j)
        acc[i][j] = __builtin_amdgcn_mfma_f32_16x16x32_bf16(af[i], bf[j], acc[i][j], 0, 0, 0);
    __syncthreads();
  }

#pragma unroll
  for (int i = 0; i < 4; ++i) {
#pragma unroll
    for (int r = 0; r < 4; ++r) {
      int o = m0 + wm * 64 + i * 16 + fq * 4 + r;
      float s  = g3p[o] * rsqrtf(v3p[o] + EPSV);
      float sh = (b3p[o] - m3p[o]) * s + be3p[o];
      float v = fmaxf(acc[i][0][r] * s + sh, 0.f) + fmaxf(acc[i][1][r] * s + sh, 0.f)
              + fmaxf(acc[i][2][r] * s + sh, 0.f) + fmaxf(acc[i][3][r] * s + sh, 0.f);
      v += __shfl_xor(v, 1); v += __shfl_xor(v, 2);
      v += __shfl_xor(v, 4); v += __shfl_xor(v, 8);
      if (fr == 0) atomicAdd(&xe_acc[b * 512 + o], v);
    }
  }
}

// --- k4: logits -> sigmoid -> gate multiply (one wave per (b,p)) ------------
__global__ __launch_bounds__(256) void k4_gate_out(
    const float* __restrict__ P2, const float* __restrict__ u,
    const float* __restrict__ t, const float* __restrict__ xe_acc,
    const float* __restrict__ w4, const float* __restrict__ b4,
    const float* __restrict__ x, float* __restrict__ out)
{
  __shared__ float us[256], ts[256];
  const int b = blockIdx.x;
  us[threadIdx.x] = u[b * 256 + threadIdx.x];
  ts[threadIdx.x] = t[b * 256 + threadIdx.x];
  __syncthreads();
  const int wave = threadIdx.x >> 6, lane = threadIdx.x & 63;
  const int p = blockIdx.y * 4 + wave;
  const float* row = P2 + ((size_t)b * 512 + p) * 512;
  float4 th = *(const float4*)&row[lane * 4];
  float4 ph = *(const float4*)&row[256 + lane * 4];
  int ki = lane * 4;
  float rs = th.x * us[ki] + th.y * us[ki + 1] + th.z * us[ki + 2] + th.w * us[ki + 3]
           + ph.x * ts[ki] + ph.y * ts[ki + 1] + ph.z * ts[ki + 2] + ph.w * ts[ki + 3];
  rs += __shfl_xor(rs, 1);  rs += __shfl_xor(rs, 2);  rs += __shfl_xor(rs, 4);
  rs += __shfl_xor(rs, 8);  rs += __shfl_xor(rs, 16); rs += __shfl_xor(rs, 32);
  float xe = xe_acc[b * 512 + p] * (1.f / 1024.f);
  float logit = w4[0] * xe + rs + b4[0];
  float a = 1.f / (1.f + expf(-logit));
  const float4* xr = (const float4*)(x + ((size_t)b * 512 + p) * 1024);
  float4* orow = (float4*)(out + ((size_t)b * 512 + p) * 1024);
#pragma unroll
  for (int r2 = 0; r2 < 4; ++r2) {
    float4 xv = xr[lane + r2 * 64];
    float4 ov; ov.x = xv.x * a; ov.y = xv.y * a; ov.z = xv.z * a; ov.w = xv.w * a;
    orow[lane + r2 * 64] = ov;
  }
}

// ===========================================================================
// FALLBACK PATH (round-1 fp32, used only if ws_size too small)
// ===========================================================================
__global__ __launch_bounds__(256) void k1_theta_phi(
    const float* __restrict__ x,
    const float* __restrict__ w1, const float* __restrict__ b1,
    const float* __restrict__ g1, const float* __restrict__ be1,
    const float* __restrict__ m1, const float* __restrict__ v1,
    const float* __restrict__ w2, const float* __restrict__ b2,
    const float* __restrict__ g2, const float* __restrict__ be2,
    const float* __restrict__ m2, const float* __restrict__ v2,
    float* __restrict__ P)
{
  __shared__ __align__(16) float Ws[32][68];
  __shared__ __align__(16) float Xs[32][68];
  const int b  = blockIdx.z;
  const int o0 = blockIdx.y * 64;
  const int c0 = blockIdx.x * 64;
  const int tid = threadIdx.x;
  const int tx = tid & 15, ty = tid >> 4;
  const float* __restrict__ Wbase = (o0 < OUTC) ? (w1 + (size_t)o0 * HWW)
                                                : (w2 + (size_t)(o0 - OUTC) * HWW);
  const float* __restrict__ xb = x + (size_t)b * CC * HWW;
  float acc[4][4] = {{0.f}};
  for (int k0 = 0; k0 < HWW; k0 += 32) {
#pragma unroll
    for (int r = 0; r < 2; ++r) {
      int id  = tid + (r << 8);
      int row = id >> 3;
      int cg  = (id & 7) << 2;
      float4 wv = *(const float4*)(Wbase + (size_t)row * HWW + k0 + cg);
      Ws[cg+0][row] = wv.x; Ws[cg+1][row] = wv.y; Ws[cg+2][row] = wv.z; Ws[cg+3][row] = wv.w;
      float4 xv = *(const float4*)(xb + (size_t)(c0 + row) * HWW + k0 + cg);
      Xs[cg+0][row] = xv.x; Xs[cg+1][row] = xv.y; Xs[cg+2][row] = xv.z; Xs[cg+3][row] = xv.w;
    }
    __syncthreads();
#pragma unroll
    for (int k = 0; k < 32; ++k) {
      float4 av = *(const float4*)&Ws[k][ty * 4];
      float4 bv = *(const float4*)&Xs[k][tx * 4];
      acc[0][0] += av.x*bv.x; acc[0][1] += av.x*bv.y; acc[0][2] += av.x*bv.z; acc[0][3] += av.x*bv.w;
      acc[1][0] += av.y*bv.x; acc[1][1] += av.y*bv.y; acc[1][2] += av.y*bv.z; acc[1][3] += av.y*bv.w;
      acc[2][0] += av.z*bv.x; acc[2][1] += av.z*bv.y; acc[2][2] += av.z*bv.z; acc[2][3] += av.z*bv.w;
      acc[3][0] += av.w*bv.x; acc[3][1] += av.w*bv.y; acc[3][2] += av.w*bv.z; acc[3][3] += av.w*bv.w;
    }
    __syncthreads();
  }
  const float *bias, *g, *be, *m, *v; int ob;
  if (o0 < OUTC) { bias = b1; g = g1; be = be1; m = m1; v = v1; ob = o0; }
  else           { bias = b2; g = g2; be = be2; m = m2; v = v2; ob = o0 - OUTC; }
#pragma unroll
  for (int i = 0; i < 4; ++i) {
    int oi = ob + ty * 4 + i;
    float sc = g[oi] * rsqrtf(v[oi] + EPSV);
    float sh = be[oi] - m[oi] * sc;
    float bb = bias[oi];
    float4 ov;
    ov.x = fmaxf((acc[i][0] + bb) * sc + sh, 0.f);
    ov.y = fmaxf((acc[i][1] + bb) * sc + sh, 0.f);
    ov.z = fmaxf((acc[i][2] + bb) * sc + sh, 0.f);
    ov.w = fmaxf((acc[i][3] + bb) * sc + sh, 0.f);
    int oo = o0 + ty * 4 + i;
    *(float4*)(P + ((size_t)b * 512 + oo) * 512 + c0 + tx * 4) = ov;
  }
}

__global__ __launch_bounds__(256) void k2_xe(
    const float* __restrict__ x, const float* __restrict__ w3,
    const float* __restrict__ b3, const float* __restrict__ g3,
    const float* __restrict__ be3, const float* __restrict__ m3,
    const float* __restrict__ v3, float* __restrict__ xe_acc)
{
  __shared__ __align__(16) float As[32][68];
  __shared__ __align__(16) float Bs[32][68];
  const int b  = blockIdx.z;
  const int o0 = blockIdx.y * 64;
  const int p0 = blockIdx.x * 64;
  const int tid = threadIdx.x;
  const int tx = tid & 15, ty = tid >> 4;
  const float* __restrict__ xb = x + (size_t)b * CC * HWW;
  float acc[4][4] = {{0.f}};
  for (int ck = 0; ck < CC; ck += 32) {
#pragma unroll
    for (int r = 0; r < 2; ++r) {
      int id  = tid + (r << 8);
      int row = id >> 3;
      int cg  = (id & 7) << 2;
      float4 wv = *(const float4*)(w3 + (size_t)(o0 + row) * CC + ck + cg);
      As[cg+0][row] = wv.x; As[cg+1][row] = wv.y; As[cg+2][row] = wv.z; As[cg+3][row] = wv.w;
      int brow = id >> 4;
      int pg   = (id & 15) << 2;
      float4 xv = *(const float4*)(xb + (size_t)(ck + brow) * HWW + p0 + pg);
      *(float4*)&Bs[brow][pg] = xv;
    }
    __syncthreads();
#pragma unroll
    for (int k = 0; k < 32; ++k) {
      float4 av = *(const float4*)&As[k][ty * 4];
      float4 bv = *(const float4*)&Bs[k][tx * 4];
      acc[0][0] += av.x*bv.x; acc[0][1] += av.x*bv.y; acc[0][2] += av.x*bv.z; acc[0][3] += av.x*bv.w;
      acc[1][0] += av.y*bv.x; acc[1][1] += av.y*bv.y; acc[1][2] += av.y*bv.z; acc[1][3] += av.y*bv.w;
      acc[2][0] += av.z*bv.x; acc[2][1] += av.z*bv.y; acc[2][2] += av.z*bv.z; acc[2][3] += av.z*bv.w;
      acc[3][0] += av.w*bv.x; acc[3][1] += av.w*bv.y; acc[3][2] += av.w*bv.z; acc[3][3] += av.w*bv.w;
    }
    __syncthreads();
  }
#pragma unroll
  for (int i = 0; i < 4; ++i) {
    int oo = o0 + ty * 4 + i;
    float sc = g3[oo] * rsqrtf(v3[oo] + EPSV);
    float sh = be3[oo] - m3[oo] * sc;
    float bb = b3[oo];
    float ps = fmaxf((acc[i][0] + bb) * sc + sh, 0.f)
             + fmaxf((acc[i][1] + bb) * sc + sh, 0.f)
             + fmaxf((acc[i][2] + bb) * sc + sh, 0.f)
             + fmaxf((acc[i][3] + bb) * sc + sh, 0.f);
    ps += __shfl_xor(ps, 1);
    ps += __shfl_xor(ps, 2);
    ps += __shfl_xor(ps, 4);
    ps += __shfl_xor(ps, 8);
    if (tx == 0) atomicAdd(&xe_acc[b * CC + oo], ps);
  }
}

__global__ __launch_bounds__(256) void k3_ut(
    const float* __restrict__ P, const float* __restrict__ w4,
    float* __restrict__ u, float* __restrict__ t)
{
  const int b = blockIdx.x;
  const int wv = threadIdx.x >> 6, lane = threadIdx.x & 63;
  const int k = blockIdx.y * 4 + wv;
  const float* __restrict__ w4a = w4 + 1;
  const float* __restrict__ w4b = w4 + 1 + CC;
  const float* __restrict__ throw_ = P + ((size_t)b * 512 + k) * 512;
  const float* __restrict__ phrow  = P + ((size_t)b * 512 + 256 + k) * 512;
  float su = 0.f, st = 0.f;
#pragma unroll
  for (int i = lane; i < CC; i += 64) {
    su += w4a[i] * phrow[i];
    st += w4b[i] * throw_[i];
  }
#pragma unroll
  for (int off = 32; off > 0; off >>= 1) {
    su += __shfl_down(su, off);
    st += __shfl_down(st, off);
  }
  if (lane == 0) { u[b * OUTC + k] = su; t[b * OUTC + k] = st; }
}

__global__ __launch_bounds__(256) void k4_gate(
    const float* __restrict__ P, const float* __restrict__ u,
    const float* __restrict__ t, const float* __restrict__ xe_acc,
    const float* __restrict__ w4, const float* __restrict__ b4,
    float* __restrict__ amul)
{
  __shared__ float us[256], ts[256];
  const int b = blockIdx.x;
  const int p = blockIdx.y * 256 + threadIdx.x;
  us[threadIdx.x] = u[b * OUTC + threadIdx.x];
  ts[threadIdx.x] = t[b * OUTC + threadIdx.x];
  __syncthreads();
  const float* __restrict__ theta = P + (size_t)b * 512 * 512;
  const float* __restrict__ phi   = theta + 256 * 512;
  float r = 0.f, s = 0.f;
#pragma unroll 8
  for (int k = 0; k < OUTC; ++k) {
    r += us[k] * theta[(size_t)k * 512 + p];
    s += ts[k] * phi[(size_t)k * 512 + p];
  }
  float xe = xe_acc[b * CC + p] * (1.0f / 1024.0f);
  float logit = w4[0] * xe + r + s + b4[0];
  amul[b * CC + p] = 1.0f / (1.0f + expf(-logit));
}

__global__ __launch_bounds__(256) void k5_out(
    const float* __restrict__ x, const float* __restrict__ amul,
    float* __restrict__ out)
{
  int i = blockIdx.x * 256 + threadIdx.x;
  float4 xv = ((const float4*)x)[i];
  float a = amul[i >> 8];
  float4 ov; ov.x = xv.x * a; ov.y = xv.y * a; ov.z = xv.z * a; ov.w = xv.w * a;
  ((float4*)out)[i] = ov;
}

// ===========================================================================
extern "C" void kernel_launch(void* const* d_in, const int* in_sizes, int n_in,
                              void* d_out, int out_size, void* d_ws, size_t ws_size,
                              hipStream_t stream)
{
  (void)in_sizes; (void)n_in; (void)out_size;
  const float* x   = (const float*)d_in[0];
  const float* w1  = (const float*)d_in[1];
  const float* b1  = (const float*)d_in[2];
  const float* g1  = (const float*)d_in[3];
  const float* be1 = (const float*)d_in[4];
  const float* m1  = (const float*)d_in[5];
  const float* v1  = (const float*)d_in[6];
  const float* w2  = (const float*)d_in[7];
  const float* b2  = (const float*)d_in[8];
  const float* g2  = (const float*)d_in[9];
  const float* be2 = (const float*)d_in[10];
  const float* m2  = (const float*)d_in[11];
  const float* v2  = (const float*)d_in[12];
  const float* w3  = (const float*)d_in[13];
  const float* b3  = (const float*)d_in[14];
  const float* g3  = (const float*)d_in[15];
  const float* be3 = (const float*)d_in[16];
  const float* m3  = (const float*)d_in[17];
  const float* v3  = (const float*)d_in[18];
  const float* w4  = (const float*)d_in[19];
  const float* b4  = (const float*)d_in[20];
  float* out = (float*)d_out;

  if (ws_size >= 136970240ull) {
    // ---- split-bf16 MFMA path ----
    float* P2     = (float*)d_ws;                       // [32][512][512] fp32
    float* xe_acc = P2 + 8388608;                       // [32][512]
    float* u      = P2 + 8404992;                       // [32][256]
    float* t      = P2 + 8413184;                       // [32][256]
    unsigned short* Xhi  = (unsigned short*)((char*)d_ws + 33685504);
    unsigned short* Xlo  = Xhi + 16777216;
    unsigned short* XThi = Xlo + 16777216;
    unsigned short* Whi  = XThi + 16777216;
    unsigned short* Wlo  = Whi + 524288;
    unsigned short* W3hi = Wlo + 524288;

    hipMemsetAsync(xe_acc, 0, 32768 * sizeof(float), stream);  // xe_acc + u + t

    prep<<<dim3(16, 8, 33), 256, 0, stream>>>(x, w1, w2, w3, Xhi, Xlo, XThi,
                                              Whi, Wlo, W3hi);
    g1_mfma<<<dim3(512), 256, 0, stream>>>(Xhi, Xlo, Whi, Wlo,
        b1, g1, be1, m1, v1, b2, g2, be2, m2, v2, w4, P2, u, t);
    g2_mfma<<<dim3(8, 4, 32), 256, 0, stream>>>(W3hi, XThi, b3, g3, be3, m3, v3, xe_acc);
    k4_gate_out<<<dim3(32, 128), 256, 0, stream>>>(P2, u, t, xe_acc, w4, b4, x, out);
  } else {
    // ---- fallback: round-1 fp32 path ----
    float* P      = (float*)d_ws;
    float* xe_acc = P + (size_t)BB * 512 * 512;
    float* u      = xe_acc + BB * CC;
    float* t      = u + BB * OUTC;
    float* amul   = t + BB * OUTC;

    hipMemsetAsync(xe_acc, 0, (size_t)BB * CC * sizeof(float), stream);

    dim3 blk(256);
    k1_theta_phi<<<dim3(8, 8, BB), blk, 0, stream>>>(x, w1, b1, g1, be1, m1, v1,
                                                     w2, b2, g2, be2, m2, v2, P);
    k2_xe<<<dim3(16, 8, BB), blk, 0, stream>>>(x, w3, b3, g3, be3, m3, v3, xe_acc);
    k3_ut<<<dim3(BB, 64), blk, 0, stream>>>(P, w4, u, t);
    k4_gate<<<dim3(BB, 2), blk, 0, stream>>>(P, u, t, xe_acc, w4, b4, amul);
    k5_out<<<dim3((BB * CC * HWW / 4) / 256), blk, 0, stream>>>(x, amul, out);
  }
}

// Round 4
// 289.098 us; speedup vs baseline: 1.0094x; 1.0094x over previous
//
#include <hip/hip_runtime.h>
#include <math.h>

#define BB   32
#define CC   512
#define HWW  1024
#define OUTC 256
#define EPSV 1e-5f

typedef __attribute__((ext_vector_type(8))) short bfrag;
typedef __attribute__((ext_vector_type(4))) float f32x4;

__device__ inline unsigned short f2bf(float x){
  unsigned int uu = __float_as_uint(x);
  uu += 0x7fff + ((uu >> 16) & 1);      // round-to-nearest-even
  return (unsigned short)(uu >> 16);
}
__device__ inline float bf2f(unsigned short h){
  return __uint_as_float(((unsigned int)h) << 16);
}

#define ASYNC16(g, l) \
  __builtin_amdgcn_global_load_lds((const __attribute__((address_space(1))) unsigned int*)(g), \
                                   (__attribute__((address_space(3))) unsigned int*)(l), 16, 0, 0)

// ===========================================================================
// MAIN PATH (split-bf16 MFMA, 3 dispatches)
// ===========================================================================

// --- prep: weight-convert + accumulator zeroing (z==32) + x hi/lo + transpose
__global__ __launch_bounds__(256) void prep(
    const float* __restrict__ x,
    const float* __restrict__ w1, const float* __restrict__ w2,
    const float* __restrict__ w3,
    unsigned short* __restrict__ Xhi, unsigned short* __restrict__ Xlo,
    unsigned short* __restrict__ XThi,
    unsigned short* __restrict__ Whi, unsigned short* __restrict__ Wlo,
    unsigned short* __restrict__ W3hi,
    float* __restrict__ accz)          // xe_acc|u|t contiguous, 32768 floats
{
  if (blockIdx.z == 32) {
    int worker = (blockIdx.y * 16 + blockIdx.x) * 256 + threadIdx.x;  // < 32768
    accz[worker] = 0.f;                 // replaces hipMemsetAsync dispatch
    for (int i = worker; i < 786432; i += 32768) {
      if (i < 524288) {
        float v = (i < 262144) ? w1[i] : w2[i - 262144];
        unsigned short h = f2bf(v);
        Whi[i] = h;
        Wlo[i] = f2bf(v - bf2f(h));
      } else {
        int j = i - 524288;
        W3hi[j] = f2bf(w3[j]);
      }
    }
    return;
  }
  __shared__ float T[64][65];
  const int b = blockIdx.z, c0 = blockIdx.y * 64, p0 = blockIdx.x * 64;
  const int tid = threadIdx.x, tr = tid >> 4, tc4 = (tid & 15) * 4;
  const float* xb = x + (size_t)b * 512 * 1024;
#pragma unroll
  for (int r = 0; r < 4; ++r) {
    int c = c0 + tr + r * 16;
    float4 v = *(const float4*)(xb + (size_t)c * 1024 + p0 + tc4);
    T[tr + r * 16][tc4 + 0] = v.x; T[tr + r * 16][tc4 + 1] = v.y;
    T[tr + r * 16][tc4 + 2] = v.z; T[tr + r * 16][tc4 + 3] = v.w;
    ushort4 h, l;
    h.x = f2bf(v.x); l.x = f2bf(v.x - bf2f(h.x));
    h.y = f2bf(v.y); l.y = f2bf(v.y - bf2f(h.y));
    h.z = f2bf(v.z); l.z = f2bf(v.z - bf2f(h.z));
    h.w = f2bf(v.w); l.w = f2bf(v.w - bf2f(h.w));
    size_t idx = (size_t)b * 524288 + (size_t)c * 1024 + p0 + tc4;
    *(ushort4*)(Xhi + idx) = h;
    *(ushort4*)(Xlo + idx) = l;
  }
  __syncthreads();
#pragma unroll
  for (int r = 0; r < 4; ++r) {
    int pl = tr + r * 16;
    ushort4 h;
    h.x = f2bf(T[tc4 + 0][pl]); h.y = f2bf(T[tc4 + 1][pl]);
    h.z = f2bf(T[tc4 + 2][pl]); h.w = f2bf(T[tc4 + 3][pl]);
    *(ushort4*)(XThi + (size_t)b * 524288 + (size_t)(p0 + pl) * 512 + c0 + tc4) = h;
  }
}

// --- gemm_fused: ids [0,1024) = g1 (128c x 64oo tiles, split-bf16, K=1024)
//                 ids [1024,2048) = g2 (128o x 128p tiles, bf16, K=512)
// g1 retile rationale: R3's 512-block grid = 2 blocks/CU -> barrier-latency
// bound at ~34% MfmaUtil. 64-wide n-tile halves acc regs and LDS (24KB) ->
// ~4 blocks/CU; g2 blocks backfill the g1 tail.
__global__ __launch_bounds__(256) void gemm_fused(
    const unsigned short* __restrict__ Xhi, const unsigned short* __restrict__ Xlo,
    const unsigned short* __restrict__ Whi, const unsigned short* __restrict__ Wlo,
    const unsigned short* __restrict__ W3hi, const unsigned short* __restrict__ XThi,
    const float* __restrict__ b1p, const float* __restrict__ g1p,
    const float* __restrict__ be1p, const float* __restrict__ m1p, const float* __restrict__ v1p,
    const float* __restrict__ b2p, const float* __restrict__ g2p,
    const float* __restrict__ be2p, const float* __restrict__ m2p, const float* __restrict__ v2p,
    const float* __restrict__ b3p, const float* __restrict__ g3p,
    const float* __restrict__ be3p, const float* __restrict__ m3p, const float* __restrict__ v3p,
    const float* __restrict__ w4,
    float* __restrict__ P2, float* __restrict__ u, float* __restrict__ t,
    float* __restrict__ xe_acc)
{
  __shared__ unsigned short smem[12288];   // 24 KB
  const int fid  = blockIdx.x;
  const int tid  = threadIdx.x;
  const int wave = tid >> 6, lane = tid & 63;
  const int lr = lane >> 2;
  const int lcs = ((lane & 3) ^ (lr & 3)) * 8;   // swizzled 16B chunk (shorts)
  const int fr = lane & 15, fq = lane >> 4;
  const int fsw = (fq ^ (fr & 3)) * 8;

  if (fid < 1024) {
    // ================= g1: P2[b][c][oo] =================
    unsigned short* sAh = smem;            // 128x32
    unsigned short* sAl = smem + 4096;     // 128x32
    unsigned short* sBh = smem + 8192;     // 64x32
    unsigned short* sBl = smem + 10240;    // 64x32
    // XCD decode: blocks sharing an X-tile (same b,c0; 8 n-tiles) -> same XCD
    const int xcd = fid & 7;
    const int n0  = ((fid >> 3) & 7) * 64;            // oo tile
    const int bc  = ((fid >> 6) << 3) | xcd;          // 0..127
    const int b   = bc >> 2;
    const int c0  = (bc & 3) * 128;
    const int wm = wave & 1, wn = wave >> 1;          // m-half 64, n-half 32

    const unsigned short* gb; unsigned short* lb; int ninst;
    if (wave == 0)      { gb = Xhi + (size_t)b * 524288 + (size_t)c0 * 1024; lb = sAh; ninst = 8; }
    else if (wave == 1) { gb = Xlo + (size_t)b * 524288 + (size_t)c0 * 1024; lb = sAl; ninst = 8; }
    else if (wave == 2) { gb = Whi + (size_t)n0 * 1024; lb = sBh; ninst = 4; }
    else                { gb = Wlo + (size_t)n0 * 1024; lb = sBl; ninst = 4; }
    gb += (size_t)lr * 1024 + lcs;

    f32x4 acc[4][2];
    const f32x4 zz = {0.f, 0.f, 0.f, 0.f};
#pragma unroll
    for (int i = 0; i < 4; ++i) { acc[i][0] = zz; acc[i][1] = zz; }

    for (int kq = 0; kq < 1024; kq += 32) {
      for (int inst = 0; inst < ninst; ++inst)
        ASYNC16(gb + (size_t)inst * 16 * 1024 + kq, lb + inst * 512);
      __syncthreads();
      bfrag ah[4], al[4], bh[2], bl[2];
#pragma unroll
      for (int i = 0; i < 4; ++i) {
        int off = (wm * 64 + i * 16 + fr) * 32 + fsw;
        ah[i] = *(const bfrag*)&sAh[off];
        al[i] = *(const bfrag*)&sAl[off];
      }
#pragma unroll
      for (int j = 0; j < 2; ++j) {
        int off = (wn * 32 + j * 16 + fr) * 32 + fsw;
        bh[j] = *(const bfrag*)&sBh[off];
        bl[j] = *(const bfrag*)&sBl[off];
      }
#pragma unroll
      for (int i = 0; i < 4; ++i)
#pragma unroll
        for (int j = 0; j < 2; ++j) {
          acc[i][j] = __builtin_amdgcn_mfma_f32_16x16x32_bf16(ah[i], bh[j], acc[i][j], 0, 0, 0);
          acc[i][j] = __builtin_amdgcn_mfma_f32_16x16x32_bf16(ah[i], bl[j], acc[i][j], 0, 0, 0);
          acc[i][j] = __builtin_amdgcn_mfma_f32_16x16x32_bf16(al[i], bh[j], acc[i][j], 0, 0, 0);
        }
      __syncthreads();
    }

    const float *bias, *gg, *bes, *mm, *vv_; int cof;
    if (n0 < 256) { bias = b1p; gg = g1p; bes = be1p; mm = m1p; vv_ = v1p; cof = 0; }
    else          { bias = b2p; gg = g2p; bes = be2p; mm = m2p; vv_ = v2p; cof = 256; }
    const float* wsel = (n0 < 256) ? (w4 + 513) : (w4 + 1);   // theta->t, phi->u
    float* dsel = (n0 < 256) ? (t + b * 256) : (u + b * 256);
    const int cobase = (n0 - cof) + wn * 32;
    float wt[4][4];
#pragma unroll
    for (int i = 0; i < 4; ++i)
#pragma unroll
      for (int r = 0; r < 4; ++r)
        wt[i][r] = wsel[c0 + wm * 64 + i * 16 + fq * 4 + r];

#pragma unroll
    for (int j = 0; j < 2; ++j) {
      int co = n0 + wn * 32 + j * 16 + fr;
      int q = co - cof;
      float s  = gg[q] * rsqrtf(vv_[q] + EPSV);
      float sh = (bias[q] - mm[q]) * s + bes[q];
      float psum = 0.f;
#pragma unroll
      for (int i = 0; i < 4; ++i) {
        int crow = c0 + wm * 64 + i * 16 + fq * 4;
        float* dst = P2 + ((size_t)b * 512 + crow) * 512 + co;
#pragma unroll
        for (int r = 0; r < 4; ++r) {
          float val = fmaxf(acc[i][j][r] * s + sh, 0.f);
          dst[(size_t)r * 512] = val;
          psum += wt[i][r] * val;
        }
      }
      psum += __shfl_xor(psum, 16);
      psum += __shfl_xor(psum, 32);
      if (fq == 0) atomicAdd(&dsel[cobase + j * 16 + fr], psum);
    }
  } else {
    // ================= g2: xe_acc[b][o] =================
    unsigned short* sA = smem;             // 128x32 (W3)
    unsigned short* sB = smem + 4096;      // 128x32 (XThi)
    const int h  = fid - 1024;
    const int n0 = (h & 7) * 128;                    // p tile
    const int m0 = ((h >> 3) & 3) * 128;             // o tile
    const int b  = h >> 5;
    const int wm = wave & 1, wn = wave >> 1;

    const unsigned short* gb; unsigned short* lb;
    if (wave < 2) { gb = W3hi + (size_t)(m0 + wave * 64) * 512; lb = sA + wave * 2048; }
    else { gb = XThi + (size_t)b * 524288 + (size_t)(n0 + (wave - 2) * 64) * 512; lb = sB + (wave - 2) * 2048; }
    gb += (size_t)lr * 512 + lcs;

    f32x4 acc[4][4];
    const f32x4 zz = {0.f, 0.f, 0.f, 0.f};
#pragma unroll
    for (int i = 0; i < 4; ++i)
#pragma unroll
      for (int j = 0; j < 4; ++j) acc[i][j] = zz;

    for (int kq = 0; kq < 512; kq += 32) {
#pragma unroll
      for (int inst = 0; inst < 4; ++inst)
        ASYNC16(gb + (size_t)inst * 16 * 512 + kq, lb + inst * 512);
      __syncthreads();
      bfrag af[4], bf[4];
#pragma unroll
      for (int i = 0; i < 4; ++i)
        af[i] = *(const bfrag*)&sA[(wm * 64 + i * 16 + fr) * 32 + fsw];
#pragma unroll
      for (int j = 0; j < 4; ++j)
        bf[j] = *(const bfrag*)&sB[(wn * 64 + j * 16 + fr) * 32 + fsw];
#pragma unroll
      for (int i = 0; i < 4; ++i)
#pragma unroll
        for (int j = 0; j < 4; ++j)
          acc[i][j] = __builtin_amdgcn_mfma_f32_16x16x32_bf16(af[i], bf[j], acc[i][j], 0, 0, 0);
      __syncthreads();
    }

#pragma unroll
    for (int i = 0; i < 4; ++i) {
#pragma unroll
      for (int r = 0; r < 4; ++r) {
        int o = m0 + wm * 64 + i * 16 + fq * 4 + r;
        float s  = g3p[o] * rsqrtf(v3p[o] + EPSV);
        float sh = (b3p[o] - m3p[o]) * s + be3p[o];
        float v = fmaxf(acc[i][0][r] * s + sh, 0.f) + fmaxf(acc[i][1][r] * s + sh, 0.f)
                + fmaxf(acc[i][2][r] * s + sh, 0.f) + fmaxf(acc[i][3][r] * s + sh, 0.f);
        v += __shfl_xor(v, 1); v += __shfl_xor(v, 2);
        v += __shfl_xor(v, 4); v += __shfl_xor(v, 8);
        if (fr == 0) atomicAdd(&xe_acc[b * 512 + o], v);
      }
    }
  }
}

// --- k4: logits -> sigmoid -> gate multiply (one wave per (b,p)) ------------
__global__ __launch_bounds__(256) void k4_gate_out(
    const float* __restrict__ P2, const float* __restrict__ u,
    const float* __restrict__ t, const float* __restrict__ xe_acc,
    const float* __restrict__ w4, const float* __restrict__ b4,
    const float* __restrict__ x, float* __restrict__ out)
{
  __shared__ float us[256], ts[256];
  const int b = blockIdx.x;
  us[threadIdx.x] = u[b * 256 + threadIdx.x];
  ts[threadIdx.x] = t[b * 256 + threadIdx.x];
  __syncthreads();
  const int wave = threadIdx.x >> 6, lane = threadIdx.x & 63;
  const int p = blockIdx.y * 4 + wave;
  const float* row = P2 + ((size_t)b * 512 + p) * 512;
  float4 th = *(const float4*)&row[lane * 4];
  float4 ph = *(const float4*)&row[256 + lane * 4];
  int ki = lane * 4;
  float rs = th.x * us[ki] + th.y * us[ki + 1] + th.z * us[ki + 2] + th.w * us[ki + 3]
           + ph.x * ts[ki] + ph.y * ts[ki + 1] + ph.z * ts[ki + 2] + ph.w * ts[ki + 3];
  rs += __shfl_xor(rs, 1);  rs += __shfl_xor(rs, 2);  rs += __shfl_xor(rs, 4);
  rs += __shfl_xor(rs, 8);  rs += __shfl_xor(rs, 16); rs += __shfl_xor(rs, 32);
  float xe = xe_acc[b * 512 + p] * (1.f / 1024.f);
  float logit = w4[0] * xe + rs + b4[0];
  float a = 1.f / (1.f + expf(-logit));
  const float4* xr = (const float4*)(x + ((size_t)b * 512 + p) * 1024);
  float4* orow = (float4*)(out + ((size_t)b * 512 + p) * 1024);
#pragma unroll
  for (int r2 = 0; r2 < 4; ++r2) {
    float4 xv = xr[lane + r2 * 64];
    float4 ov; ov.x = xv.x * a; ov.y = xv.y * a; ov.z = xv.z * a; ov.w = xv.w * a;
    orow[lane + r2 * 64] = ov;
  }
}

// ===========================================================================
// FALLBACK PATH (round-1 fp32, used only if ws_size too small)
// ===========================================================================
__global__ __launch_bounds__(256) void k1_theta_phi(
    const float* __restrict__ x,
    const float* __restrict__ w1, const float* __restrict__ b1,
    const float* __restrict__ g1, const float* __restrict__ be1,
    const float* __restrict__ m1, const float* __restrict__ v1,
    const float* __restrict__ w2, const float* __restrict__ b2,
    const float* __restrict__ g2, const float* __restrict__ be2,
    const float* __restrict__ m2, const float* __restrict__ v2,
    float* __restrict__ P)
{
  __shared__ __align__(16) float Ws[32][68];
  __shared__ __align__(16) float Xs[32][68];
  const int b  = blockIdx.z;
  const int o0 = blockIdx.y * 64;
  const int c0 = blockIdx.x * 64;
  const int tid = threadIdx.x;
  const int tx = tid & 15, ty = tid >> 4;
  const float* __restrict__ Wbase = (o0 < OUTC) ? (w1 + (size_t)o0 * HWW)
                                                : (w2 + (size_t)(o0 - OUTC) * HWW);
  const float* __restrict__ xb = x + (size_t)b * CC * HWW;
  float acc[4][4] = {{0.f}};
  for (int k0 = 0; k0 < HWW; k0 += 32) {
#pragma unroll
    for (int r = 0; r < 2; ++r) {
      int id  = tid + (r << 8);
      int row = id >> 3;
      int cg  = (id & 7) << 2;
      float4 wv = *(const float4*)(Wbase + (size_t)row * HWW + k0 + cg);
      Ws[cg+0][row] = wv.x; Ws[cg+1][row] = wv.y; Ws[cg+2][row] = wv.z; Ws[cg+3][row] = wv.w;
      float4 xv = *(const float4*)(xb + (size_t)(c0 + row) * HWW + k0 + cg);
      Xs[cg+0][row] = xv.x; Xs[cg+1][row] = xv.y; Xs[cg+2][row] = xv.z; Xs[cg+3][row] = xv.w;
    }
    __syncthreads();
#pragma unroll
    for (int k = 0; k < 32; ++k) {
      float4 av = *(const float4*)&Ws[k][ty * 4];
      float4 bv = *(const float4*)&Xs[k][tx * 4];
      acc[0][0] += av.x*bv.x; acc[0][1] += av.x*bv.y; acc[0][2] += av.x*bv.z; acc[0][3] += av.x*bv.w;
      acc[1][0] += av.y*bv.x; acc[1][1] += av.y*bv.y; acc[1][2] += av.y*bv.z; acc[1][3] += av.y*bv.w;
      acc[2][0] += av.z*bv.x; acc[2][1] += av.z*bv.y; acc[2][2] += av.z*bv.z; acc[2][3] += av.z*bv.w;
      acc[3][0] += av.w*bv.x; acc[3][1] += av.w*bv.y; acc[3][2] += av.w*bv.z; acc[3][3] += av.w*bv.w;
    }
    __syncthreads();
  }
  const float *bias, *g, *be, *m, *v; int ob;
  if (o0 < OUTC) { bias = b1; g = g1; be = be1; m = m1; v = v1; ob = o0; }
  else           { bias = b2; g = g2; be = be2; m = m2; v = v2; ob = o0 - OUTC; }
#pragma unroll
  for (int i = 0; i < 4; ++i) {
    int oi = ob + ty * 4 + i;
    float sc = g[oi] * rsqrtf(v[oi] + EPSV);
    float sh = be[oi] - m[oi] * sc;
    float bb = bias[oi];
    float4 ov;
    ov.x = fmaxf((acc[i][0] + bb) * sc + sh, 0.f);
    ov.y = fmaxf((acc[i][1] + bb) * sc + sh, 0.f);
    ov.z = fmaxf((acc[i][2] + bb) * sc + sh, 0.f);
    ov.w = fmaxf((acc[i][3] + bb) * sc + sh, 0.f);
    int oo = o0 + ty * 4 + i;
    *(float4*)(P + ((size_t)b * 512 + oo) * 512 + c0 + tx * 4) = ov;
  }
}

__global__ __launch_bounds__(256) void k2_xe(
    const float* __restrict__ x, const float* __restrict__ w3,
    const float* __restrict__ b3, const float* __restrict__ g3,
    const float* __restrict__ be3, const float* __restrict__ m3,
    const float* __restrict__ v3, float* __restrict__ xe_acc)
{
  __shared__ __align__(16) float As[32][68];
  __shared__ __align__(16) float Bs[32][68];
  const int b  = blockIdx.z;
  const int o0 = blockIdx.y * 64;
  const int p0 = blockIdx.x * 64;
  const int tid = threadIdx.x;
  const int tx = tid & 15, ty = tid >> 4;
  const float* __restrict__ xb = x + (size_t)b * CC * HWW;
  float acc[4][4] = {{0.f}};
  for (int ck = 0; ck < CC; ck += 32) {
#pragma unroll
    for (int r = 0; r < 2; ++r) {
      int id  = tid + (r << 8);
      int row = id >> 3;
      int cg  = (id & 7) << 2;
      float4 wv = *(const float4*)(w3 + (size_t)(o0 + row) * CC + ck + cg);
      As[cg+0][row] = wv.x; As[cg+1][row] = wv.y; As[cg+2][row] = wv.z; As[cg+3][row] = wv.w;
      int brow = id >> 4;
      int pg   = (id & 15) << 2;
      float4 xv = *(const float4*)(xb + (size_t)(ck + brow) * HWW + p0 + pg);
      *(float4*)&Bs[brow][pg] = xv;
    }
    __syncthreads();
#pragma unroll
    for (int k = 0; k < 32; ++k) {
      float4 av = *(const float4*)&As[k][ty * 4];
      float4 bv = *(const float4*)&Bs[k][tx * 4];
      acc[0][0] += av.x*bv.x; acc[0][1] += av.x*bv.y; acc[0][2] += av.x*bv.z; acc[0][3] += av.x*bv.w;
      acc[1][0] += av.y*bv.x; acc[1][1] += av.y*bv.y; acc[1][2] += av.y*bv.z; acc[1][3] += av.y*bv.w;
      acc[2][0] += av.z*bv.x; acc[2][1] += av.z*bv.y; acc[2][2] += av.z*bv.z; acc[2][3] += av.z*bv.w;
      acc[3][0] += av.w*bv.x; acc[3][1] += av.w*bv.y; acc[3][2] += av.w*bv.z; acc[3][3] += av.w*bv.w;
    }
    __syncthreads();
  }
#pragma unroll
  for (int i = 0; i < 4; ++i) {
    int oo = o0 + ty * 4 + i;
    float sc = g3[oo] * rsqrtf(v3[oo] + EPSV);
    float sh = be3[oo] - m3[oo] * sc;
    float bb = b3[oo];
    float ps = fmaxf((acc[i][0] + bb) * sc + sh, 0.f)
             + fmaxf((acc[i][1] + bb) * sc + sh, 0.f)
             + fmaxf((acc[i][2] + bb) * sc + sh, 0.f)
             + fmaxf((acc[i][3] + bb) * sc + sh, 0.f);
    ps += __shfl_xor(ps, 1);
    ps += __shfl_xor(ps, 2);
    ps += __shfl_xor(ps, 4);
    ps += __shfl_xor(ps, 8);
    if (tx == 0) atomicAdd(&xe_acc[b * CC + oo], ps);
  }
}

__global__ __launch_bounds__(256) void k3_ut(
    const float* __restrict__ P, const float* __restrict__ w4,
    float* __restrict__ u, float* __restrict__ t)
{
  const int b = blockIdx.x;
  const int wv = threadIdx.x >> 6, lane = threadIdx.x & 63;
  const int k = blockIdx.y * 4 + wv;
  const float* __restrict__ w4a = w4 + 1;
  const float* __restrict__ w4b = w4 + 1 + CC;
  const float* __restrict__ throw_ = P + ((size_t)b * 512 + k) * 512;
  const float* __restrict__ phrow  = P + ((size_t)b * 512 + 256 + k) * 512;
  float su = 0.f, st = 0.f;
#pragma unroll
  for (int i = lane; i < CC; i += 64) {
    su += w4a[i] * phrow[i];
    st += w4b[i] * throw_[i];
  }
#pragma unroll
  for (int off = 32; off > 0; off >>= 1) {
    su += __shfl_down(su, off);
    st += __shfl_down(st, off);
  }
  if (lane == 0) { u[b * OUTC + k] = su; t[b * OUTC + k] = st; }
}

__global__ __launch_bounds__(256) void k4_gate(
    const float* __restrict__ P, const float* __restrict__ u,
    const float* __restrict__ t, const float* __restrict__ xe_acc,
    const float* __restrict__ w4, const float* __restrict__ b4,
    float* __restrict__ amul)
{
  __shared__ float us[256], ts[256];
  const int b = blockIdx.x;
  const int p = blockIdx.y * 256 + threadIdx.x;
  us[threadIdx.x] = u[b * OUTC + threadIdx.x];
  ts[threadIdx.x] = t[b * OUTC + threadIdx.x];
  __syncthreads();
  const float* __restrict__ theta = P + (size_t)b * 512 * 512;
  const float* __restrict__ phi   = theta + 256 * 512;
  float r = 0.f, s = 0.f;
#pragma unroll 8
  for (int k = 0; k < OUTC; ++k) {
    r += us[k] * theta[(size_t)k * 512 + p];
    s += ts[k] * phi[(size_t)k * 512 + p];
  }
  float xe = xe_acc[b * CC + p] * (1.0f / 1024.0f);
  float logit = w4[0] * xe + r + s + b4[0];
  amul[b * CC + p] = 1.0f / (1.0f + expf(-logit));
}

__global__ __launch_bounds__(256) void k5_out(
    const float* __restrict__ x, const float* __restrict__ amul,
    float* __restrict__ out)
{
  int i = blockIdx.x * 256 + threadIdx.x;
  float4 xv = ((const float4*)x)[i];
  float a = amul[i >> 8];
  float4 ov; ov.x = xv.x * a; ov.y = xv.y * a; ov.z = xv.z * a; ov.w = xv.w * a;
  ((float4*)out)[i] = ov;
}

// ===========================================================================
extern "C" void kernel_launch(void* const* d_in, const int* in_sizes, int n_in,
                              void* d_out, int out_size, void* d_ws, size_t ws_size,
                              hipStream_t stream)
{
  (void)in_sizes; (void)n_in; (void)out_size;
  const float* x   = (const float*)d_in[0];
  const float* w1  = (const float*)d_in[1];
  const float* b1  = (const float*)d_in[2];
  const float* g1  = (const float*)d_in[3];
  const float* be1 = (const float*)d_in[4];
  const float* m1  = (const float*)d_in[5];
  const float* v1  = (const float*)d_in[6];
  const float* w2  = (const float*)d_in[7];
  const float* b2  = (const float*)d_in[8];
  const float* g2  = (const float*)d_in[9];
  const float* be2 = (const float*)d_in[10];
  const float* m2  = (const float*)d_in[11];
  const float* v2  = (const float*)d_in[12];
  const float* w3  = (const float*)d_in[13];
  const float* b3  = (const float*)d_in[14];
  const float* g3  = (const float*)d_in[15];
  const float* be3 = (const float*)d_in[16];
  const float* m3  = (const float*)d_in[17];
  const float* v3  = (const float*)d_in[18];
  const float* w4  = (const float*)d_in[19];
  const float* b4  = (const float*)d_in[20];
  float* out = (float*)d_out;

  if (ws_size >= 136970240ull) {
    // ---- split-bf16 MFMA path, 3 dispatches ----
    float* P2     = (float*)d_ws;                       // [32][512][512] fp32
    float* xe_acc = P2 + 8388608;                       // [32][512]
    float* u      = P2 + 8404992;                       // [32][256]
    float* t      = P2 + 8413184;                       // [32][256]
    unsigned short* Xhi  = (unsigned short*)((char*)d_ws + 33685504);
    unsigned short* Xlo  = Xhi + 16777216;
    unsigned short* XThi = Xlo + 16777216;
    unsigned short* Whi  = XThi + 16777216;
    unsigned short* Wlo  = Whi + 524288;
    unsigned short* W3hi = Wlo + 524288;

    prep<<<dim3(16, 8, 33), 256, 0, stream>>>(x, w1, w2, w3, Xhi, Xlo, XThi,
                                              Whi, Wlo, W3hi, xe_acc);
    gemm_fused<<<dim3(2048), 256, 0, stream>>>(Xhi, Xlo, Whi, Wlo, W3hi, XThi,
        b1, g1, be1, m1, v1, b2, g2, be2, m2, v2, b3, g3, be3, m3, v3,
        w4, P2, u, t, xe_acc);
    k4_gate_out<<<dim3(32, 128), 256, 0, stream>>>(P2, u, t, xe_acc, w4, b4, x, out);
  } else {
    // ---- fallback: round-1 fp32 path ----
    float* P      = (float*)d_ws;
    float* xe_acc = P + (size_t)BB * 512 * 512;
    float* u      = xe_acc + BB * CC;
    float* t      = u + BB * OUTC;
    float* amul   = t + BB * OUTC;

    hipMemsetAsync(xe_acc, 0, (size_t)BB * CC * sizeof(float), stream);

    dim3 blk(256);
    k1_theta_phi<<<dim3(8, 8, BB), blk, 0, stream>>>(x, w1, b1, g1, be1, m1, v1,
                                                     w2, b2, g2, be2, m2, v2, P);
    k2_xe<<<dim3(16, 8, BB), blk, 0, stream>>>(x, w3, b3, g3, be3, m3, v3, xe_acc);
    k3_ut<<<dim3(BB, 64), blk, 0, stream>>>(P, w4, u, t);
    k4_gate<<<dim3(BB, 2), blk, 0, stream>>>(P, u, t, xe_acc, w4, b4, amul);
    k5_out<<<dim3((BB * CC * HWW / 4) / 256), blk, 0, stream>>>(x, amul, out);
  }
}